// Round 1
// baseline (667.480 us; speedup 1.0000x reference)
//
#include <hip/hip_runtime.h>
#include <math.h>

#define NB 2
#define NN 512
#define CS 256
#define CP 128
#define FD 64
#define NBINS 22
#define EPB 64        // edges per block
#define PAD 132       // padded row stride (floats) for [64][128] LDS tiles

// ---------------------------------------------------------------------------
// Kernel A: per-node precompute.
//   p[n]   = x[n] @ Wsp + bsp                         [1024 x 64]
//   q[n,c] = b1[c] + diffuse[n]*W1[172,c] + sum_k p[n,k]*W1[k,c]
//   r[n,c] =         diffuse[n]*W1[173,c] + sum_k p[n,k]*W1[64+k,c]
// ws layout: q at ws[0 .. 1024*128), r at ws[1024*128 .. 2*1024*128)
// ---------------------------------------------------------------------------
__global__ __launch_bounds__(256) void ef_node_kernel(
    const float* __restrict__ x,
    const float* __restrict__ diffuse,
    const float* __restrict__ Wsp,
    const float* __restrict__ bsp,
    const float* __restrict__ W1,
    const float* __restrict__ b1,
    float* __restrict__ qr)
{
    __shared__ float xs[CS];
    __shared__ float ps[FD];
    const int n = blockIdx.x;
    const int t = threadIdx.x;
    xs[t] = x[(size_t)n * CS + t];
    __syncthreads();
    if (t < FD) {
        float acc = bsp[t];
        #pragma unroll 8
        for (int k = 0; k < CS; ++k)
            acc = fmaf(xs[k], Wsp[k * FD + t], acc);
        ps[t] = acc;
    }
    __syncthreads();
    const float dm = diffuse[n];
    const int c = t & (CP - 1);
    if (t < CP) {
        float acc = b1[c] + dm * W1[172 * CP + c];
        #pragma unroll 8
        for (int k = 0; k < FD; ++k)
            acc = fmaf(ps[k], W1[k * CP + c], acc);
        qr[(size_t)n * CP + c] = acc;
    } else {
        float acc = dm * W1[173 * CP + c];
        #pragma unroll 8
        for (int k = 0; k < FD; ++k)
            acc = fmaf(ps[k], W1[(FD + k) * CP + c], acc);
        qr[(size_t)(1024 + n) * CP + c] = acc;
    }
}

// ---------------------------------------------------------------------------
// GEMM micro-tile helper: acc[4][8] += bufIn[e0+ee][k] * W[k][o0+oo]
// bufIn is an LDS [EPB][PAD] tile; W is a global [128][128] matrix.
// ---------------------------------------------------------------------------
__device__ __forceinline__ void gemm_tile(const float* __restrict__ bufIn,
                                          const float* __restrict__ W,
                                          float acc[4][8], int e0, int o0)
{
    for (int k = 0; k < CP; k += 4) {
        float4 hv[4];
        #pragma unroll
        for (int ee = 0; ee < 4; ++ee)
            hv[ee] = *(const float4*)&bufIn[(e0 + ee) * PAD + k];
        #pragma unroll
        for (int kk = 0; kk < 4; ++kk) {
            const float4 wa = *(const float4*)&W[(k + kk) * CP + o0];
            const float4 wb = *(const float4*)&W[(k + kk) * CP + o0 + 4];
            const float w[8] = {wa.x, wa.y, wa.z, wa.w, wb.x, wb.y, wb.z, wb.w};
            #pragma unroll
            for (int ee = 0; ee < 4; ++ee) {
                const float h = (kk == 0) ? hv[ee].x
                              : (kk == 1) ? hv[ee].y
                              : (kk == 2) ? hv[ee].z : hv[ee].w;
                #pragma unroll
                for (int oo = 0; oo < 8; ++oo)
                    acc[ee][oo] = fmaf(h, w[oo], acc[ee][oo]);
            }
        }
    }
}

// ---------------------------------------------------------------------------
// Kernel B: fused per-edge pipeline for a 64-edge tile (fixed b,i; 64 j's).
// ---------------------------------------------------------------------------
__global__ __launch_bounds__(256) void ef_edge_kernel(
    const float* __restrict__ trans_t,
    const float* __restrict__ trans_sc,
    const float* __restrict__ edge_mask,
    const float* __restrict__ W1,
    const float* __restrict__ W2,
    const float* __restrict__ b2,
    const float* __restrict__ W3,
    const float* __restrict__ b3,
    const float* __restrict__ ln_g,
    const float* __restrict__ ln_b,
    const float* __restrict__ qr,
    float* __restrict__ out)
{
    __shared__ float bufA[EPB * PAD];   // r-stage, then h2
    __shared__ float bufB[EPB * PAD];   // h1, then h3
    __shared__ float qs[CP];
    __shared__ int rowT[EPB];
    __shared__ int rowS[EPB];

    const int t   = threadIdx.x;
    const int blk = blockIdx.x;
    const int jt  = blk & 7;
    const int i   = (blk >> 3) & (NN - 1);
    const int b   = blk >> 12;          // NN*(NN/EPB) = 4096 = 2^12
    const int j0  = jt * EPB;
    const int nodeI  = b * NN + i;
    const int nodeJ0 = b * NN + j0;

    // --- stage r rows (64x128 contiguous) into bufA; q row into qs ---
    {
        const float4* src = (const float4*)(qr + (size_t)(1024 + nodeJ0) * CP);
        for (int v = t; v < EPB * CP / 4; v += 256) {
            const float4 val = src[v];
            const int e  = v >> 5;      // 32 float4 per 128-float row
            const int c4 = v & 31;
            *(float4*)&bufA[e * PAD + c4 * 4] = val;
        }
        if (t < CP / 4)
            ((float4*)qs)[t] = ((const float4*)(qr + (size_t)nodeI * CP))[t];
    }

    // --- distogram bins (exact fp32 replication of jnp.linspace semantics) ---
    if (t < EPB) {
        const float step = __fdiv_rn(__fsub_rn(20.0f, 0.001f), 21.0f);
        const int nj = nodeJ0 + t;
        #pragma unroll
        for (int which = 0; which < 2; ++which) {
            const float* pos = which ? trans_sc : trans_t;
            const float dx = __fsub_rn(pos[nodeI * 3 + 0], pos[nj * 3 + 0]);
            const float dy = __fsub_rn(pos[nodeI * 3 + 1], pos[nj * 3 + 1]);
            const float dz = __fsub_rn(pos[nodeI * 3 + 2], pos[nj * 3 + 2]);
            const float s = __fadd_rn(__fadd_rn(__fmul_rn(dx, dx), __fmul_rn(dy, dy)),
                                      __fmul_rn(dz, dz));
            const float d = sqrtf(s);
            int row = -1;
            for (int k = 0; k < NBINS; ++k) {
                const float lo = __fadd_rn(0.001f, __fmul_rn((float)k, step));
                const float hi = (k == NBINS - 1)
                               ? 1e8f
                               : __fadd_rn(0.001f, __fmul_rn((float)(k + 1), step));
                if (d > lo && d < hi) row = (which ? 150 : 128) + k;
            }
            if (which) rowS[t] = row; else rowT[t] = row;
        }
    }
    __syncthreads();

    // --- h1 = relu(q_i + r_j + W1[distrow] + W1[screw]) -> bufB ---
    {
        const int e  = t >> 2;
        const int c0 = (t & 3) * 32;
        const int rT = rowT[e], rS = rowS[e];
        const float* wT = W1 + (size_t)(rT < 0 ? 0 : rT) * CP;
        const float* wS = W1 + (size_t)(rS < 0 ? 0 : rS) * CP;
        const float fT = (rT < 0) ? 0.0f : 1.0f;
        const float fS = (rS < 0) ? 0.0f : 1.0f;
        #pragma unroll
        for (int c = c0; c < c0 + 32; c += 4) {
            float4 v        = *(const float4*)&qs[c];
            const float4 r4 = *(const float4*)&bufA[e * PAD + c];
            const float4 wt = *(const float4*)&wT[c];
            const float4 ws = *(const float4*)&wS[c];
            v.x = fmaxf(v.x + r4.x + fT * wt.x + fS * ws.x, 0.0f);
            v.y = fmaxf(v.y + r4.y + fT * wt.y + fS * ws.y, 0.0f);
            v.z = fmaxf(v.z + r4.z + fT * wt.z + fS * ws.z, 0.0f);
            v.w = fmaxf(v.w + r4.w + fT * wt.w + fS * ws.w, 0.0f);
            *(float4*)&bufB[e * PAD + c] = v;
        }
    }
    __syncthreads();

    const int eg = t & 15, og = t >> 4;
    const int e0 = eg * 4, o0 = og * 8;

    // --- layer 2: h2 = relu(h1 @ W2 + b2), bufB -> bufA ---
    {
        float acc[4][8];
        #pragma unroll
        for (int oo = 0; oo < 8; ++oo) {
            const float bv = b2[o0 + oo];
            #pragma unroll
            for (int ee = 0; ee < 4; ++ee) acc[ee][oo] = bv;
        }
        gemm_tile(bufB, W2, acc, e0, o0);
        #pragma unroll
        for (int ee = 0; ee < 4; ++ee) {
            float4 s0, s1;
            s0.x = fmaxf(acc[ee][0], 0.0f); s0.y = fmaxf(acc[ee][1], 0.0f);
            s0.z = fmaxf(acc[ee][2], 0.0f); s0.w = fmaxf(acc[ee][3], 0.0f);
            s1.x = fmaxf(acc[ee][4], 0.0f); s1.y = fmaxf(acc[ee][5], 0.0f);
            s1.z = fmaxf(acc[ee][6], 0.0f); s1.w = fmaxf(acc[ee][7], 0.0f);
            *(float4*)&bufA[(e0 + ee) * PAD + o0]     = s0;
            *(float4*)&bufA[(e0 + ee) * PAD + o0 + 4] = s1;
        }
    }
    __syncthreads();

    // --- layer 3: h3 = h2 @ W3 + b3, bufA -> bufB ---
    {
        float acc[4][8];
        #pragma unroll
        for (int oo = 0; oo < 8; ++oo) {
            const float bv = b3[o0 + oo];
            #pragma unroll
            for (int ee = 0; ee < 4; ++ee) acc[ee][oo] = bv;
        }
        gemm_tile(bufA, W3, acc, e0, o0);
        #pragma unroll
        for (int ee = 0; ee < 4; ++ee) {
            float4 s0, s1;
            s0.x = acc[ee][0]; s0.y = acc[ee][1]; s0.z = acc[ee][2]; s0.w = acc[ee][3];
            s1.x = acc[ee][4]; s1.y = acc[ee][5]; s1.z = acc[ee][6]; s1.w = acc[ee][7];
            *(float4*)&bufB[(e0 + ee) * PAD + o0]     = s0;
            *(float4*)&bufB[(e0 + ee) * PAD + o0 + 4] = s1;
        }
    }
    __syncthreads();

    // --- LayerNorm (two-pass, exact mean/var), mask, store ---
    {
        const int e  = t >> 2;
        const int c0 = (t & 3) * 32;
        float vals[32];
        float s = 0.0f;
        #pragma unroll
        for (int cc = 0; cc < 32; cc += 4) {
            const float4 v = *(const float4*)&bufB[e * PAD + c0 + cc];
            vals[cc] = v.x; vals[cc + 1] = v.y; vals[cc + 2] = v.z; vals[cc + 3] = v.w;
            s += v.x + v.y + v.z + v.w;
        }
        s += __shfl_xor(s, 1);
        s += __shfl_xor(s, 2);
        const float mu = s * (1.0f / 128.0f);
        float s2 = 0.0f;
        #pragma unroll
        for (int cc = 0; cc < 32; ++cc) {
            const float d = vals[cc] - mu;
            s2 = fmaf(d, d, s2);
        }
        s2 += __shfl_xor(s2, 1);
        s2 += __shfl_xor(s2, 2);
        const float inv = rsqrtf(s2 * (1.0f / 128.0f) + 1e-5f);
        const size_t erow = ((size_t)(b * NN + i)) * NN + (j0 + e);
        const float em = edge_mask[erow];
        float* op = out + erow * CP + c0;
        #pragma unroll
        for (int cc = 0; cc < 32; cc += 4) {
            const float4 g  = *(const float4*)&ln_g[c0 + cc];
            const float4 be = *(const float4*)&ln_b[c0 + cc];
            float4 o4;
            o4.x = ((vals[cc + 0] - mu) * inv * g.x + be.x) * em;
            o4.y = ((vals[cc + 1] - mu) * inv * g.y + be.y) * em;
            o4.z = ((vals[cc + 2] - mu) * inv * g.z + be.z) * em;
            o4.w = ((vals[cc + 3] - mu) * inv * g.w + be.w) * em;
            *(float4*)&op[cc] = o4;
        }
    }
}

extern "C" void kernel_launch(void* const* d_in, const int* in_sizes, int n_in,
                              void* d_out, int out_size, void* d_ws, size_t ws_size,
                              hipStream_t stream) {
    const float* init_node = (const float*)d_in[0];
    const float* trans_t   = (const float*)d_in[1];
    const float* trans_sc  = (const float*)d_in[2];
    const float* edge_mask = (const float*)d_in[3];
    const float* diffuse   = (const float*)d_in[4];
    const float* Wsp       = (const float*)d_in[5];
    const float* bsp       = (const float*)d_in[6];
    const float* W1        = (const float*)d_in[7];
    const float* b1        = (const float*)d_in[8];
    const float* W2        = (const float*)d_in[9];
    const float* b2        = (const float*)d_in[10];
    const float* W3        = (const float*)d_in[11];
    const float* b3        = (const float*)d_in[12];
    const float* ln_g      = (const float*)d_in[13];
    const float* ln_b      = (const float*)d_in[14];
    float* out = (float*)d_out;
    float* qr  = (float*)d_ws;   // 2 * 1024 * 128 floats = 1 MiB

    ef_node_kernel<<<NB * NN, 256, 0, stream>>>(init_node, diffuse, Wsp, bsp, W1, b1, qr);
    ef_edge_kernel<<<NB * NN * (NN / EPB), 256, 0, stream>>>(
        trans_t, trans_sc, edge_mask, W1, W2, b2, W3, b3, ln_g, ln_b, qr, out);
}

// Round 2
// 256.873 us; speedup vs baseline: 2.5985x; 2.5985x over previous
//
#include <hip/hip_runtime.h>
#include <math.h>

#define NB 2
#define NN 512
#define CS 256
#define CP 128
#define FD 64
#define NBINS 22
#define EPB 64        // edges per block

typedef __attribute__((ext_vector_type(8))) short bf16x8;
typedef __attribute__((ext_vector_type(4))) short bf16x4;
typedef __attribute__((ext_vector_type(4))) float f32x4;

__device__ __forceinline__ unsigned short f2bf_rne(float x) {
    unsigned int u = __float_as_uint(x);
    unsigned int r = (u + 0x7fffu + ((u >> 16) & 1u)) >> 16;
    return (unsigned short)r;
}
__device__ __forceinline__ float bf2f(unsigned short b) {
    return __uint_as_float(((unsigned int)b) << 16);
}

// ---------------------------------------------------------------------------
// Kernel A: per-node precompute (unchanged from round 1).
//   q[n,c] = b1[c] + diffuse[n]*W1[172,c] + sum_k p[n,k]*W1[k,c]
//   r[n,c] =         diffuse[n]*W1[173,c] + sum_k p[n,k]*W1[64+k,c]
// ---------------------------------------------------------------------------
__global__ __launch_bounds__(256) void ef_node_kernel(
    const float* __restrict__ x,
    const float* __restrict__ diffuse,
    const float* __restrict__ Wsp,
    const float* __restrict__ bsp,
    const float* __restrict__ W1,
    const float* __restrict__ b1,
    float* __restrict__ qr)
{
    __shared__ float xs[CS];
    __shared__ float ps[FD];
    const int n = blockIdx.x;
    const int t = threadIdx.x;
    xs[t] = x[(size_t)n * CS + t];
    __syncthreads();
    if (t < FD) {
        float acc = bsp[t];
        #pragma unroll 8
        for (int k = 0; k < CS; ++k)
            acc = fmaf(xs[k], Wsp[k * FD + t], acc);
        ps[t] = acc;
    }
    __syncthreads();
    const float dm = diffuse[n];
    const int c = t & (CP - 1);
    if (t < CP) {
        float acc = b1[c] + dm * W1[172 * CP + c];
        #pragma unroll 8
        for (int k = 0; k < FD; ++k)
            acc = fmaf(ps[k], W1[k * CP + c], acc);
        qr[(size_t)n * CP + c] = acc;
    } else {
        float acc = dm * W1[173 * CP + c];
        #pragma unroll 8
        for (int k = 0; k < FD; ++k)
            acc = fmaf(ps[k], W1[(FD + k) * CP + c], acc);
        qr[(size_t)(1024 + n) * CP + c] = acc;
    }
}

// ---------------------------------------------------------------------------
// Kernel P: pack W2, W3 into per-lane MFMA A-fragment order, bf16 hi/lo.
// A = W^T (M = out-channel n, K = in-channel k).
// Fragment (16x16x32): lane l holds m = l&15, k = 8*(l>>4) + j, j=0..7.
// Wp layout: [4][16384] ushort: W2h, W2l, W3h, W3l.
// slot s = ((ki*8 + mt)*64 + lane)*8 + j
// ---------------------------------------------------------------------------
__global__ __launch_bounds__(256) void ef_pack_kernel(
    const float* __restrict__ W2,
    const float* __restrict__ W3,
    unsigned short* __restrict__ Wp)
{
    const int s = blockIdx.x * 256 + threadIdx.x;   // 0..16383
    const int j    = s & 7;
    const int lane = (s >> 3) & 63;
    const int mt   = (s >> 9) & 7;
    const int ki   = s >> 12;
    const int k = 32 * ki + 8 * (lane >> 4) + j;
    const int n = 16 * mt + (lane & 15);
    const float w2 = W2[k * CP + n];
    const float w3 = W3[k * CP + n];
    const unsigned short h2 = f2bf_rne(w2);
    const unsigned short l2 = f2bf_rne(w2 - bf2f(h2));
    const unsigned short h3 = f2bf_rne(w3);
    const unsigned short l3 = f2bf_rne(w3 - bf2f(h3));
    Wp[s]         = h2;
    Wp[16384 + s] = l2;
    Wp[32768 + s] = h3;
    Wp[49152 + s] = l3;
}

// ---------------------------------------------------------------------------
// Kernel B: fused edge pipeline, MFMA (bf16 hi/lo split) in transposed space.
// Per block: 64 edges (fixed b,i; 64 j) x 128 channels. 256 threads = 4 waves.
//   P0 bins -> P1 h1(bf16 hi/lo -> LDS) -> P2 MFMA L2 -> P3 h2 -> P4 MFMA L3
//   -> P5 h3(f32 -> LDS) -> P6 LayerNorm + mask + store
// ---------------------------------------------------------------------------
__global__ __launch_bounds__(256, 4) void ef_edge_kernel(
    const float* __restrict__ trans_t,
    const float* __restrict__ trans_sc,
    const float* __restrict__ edge_mask,
    const float* __restrict__ W1,
    const float* __restrict__ b2,
    const float* __restrict__ b3,
    const float* __restrict__ ln_g,
    const float* __restrict__ ln_b,
    const float* __restrict__ qr,
    const unsigned short* __restrict__ Wp,
    float* __restrict__ out)
{
    __shared__ unsigned short hb[16384];   // 32KB: [h1h|h1l] -> [h2h|h2l] -> h3(f32)
    __shared__ int rTs[EPB];
    __shared__ int rSs[EPB];
    char* hb8 = (char*)hb;

    const int t   = threadIdx.x;
    const int blk = blockIdx.x;
    const int jt  = blk & 7;
    const int i   = (blk >> 3) & (NN - 1);
    const int b   = blk >> 12;
    const int j0  = jt * EPB;
    const int nodeI  = b * NN + i;
    const int nodeJ0 = b * NN + j0;

    // ---- P0: distogram bins (exact fp32) ----
    if (t < EPB) {
        const float step = __fdiv_rn(__fsub_rn(20.0f, 0.001f), 21.0f);
        const int nj = nodeJ0 + t;
        #pragma unroll
        for (int which = 0; which < 2; ++which) {
            const float* pos = which ? trans_sc : trans_t;
            const float dx = __fsub_rn(pos[nodeI * 3 + 0], pos[nj * 3 + 0]);
            const float dy = __fsub_rn(pos[nodeI * 3 + 1], pos[nj * 3 + 1]);
            const float dz = __fsub_rn(pos[nodeI * 3 + 2], pos[nj * 3 + 2]);
            const float s = __fadd_rn(__fadd_rn(__fmul_rn(dx, dx), __fmul_rn(dy, dy)),
                                      __fmul_rn(dz, dz));
            const float d = sqrtf(s);
            int row = -1;
            for (int k = 0; k < NBINS; ++k) {
                const float lo = __fadd_rn(0.001f, __fmul_rn((float)k, step));
                const float hi = (k == NBINS - 1)
                               ? 1e8f
                               : __fadd_rn(0.001f, __fmul_rn((float)(k + 1), step));
                if (d > lo && d < hi) row = (which ? 150 : 128) + k;
            }
            if (which) rSs[t] = row; else rTs[t] = row;
        }
    }
    __syncthreads();

    // ---- P1: h1 = relu(q_i + r_j + W1[binT] + W1[binS]), split bf16 hi/lo ----
    {
        const int e1 = t & 63;
        const int cb = t >> 6;
        const int rT = rTs[e1], rS = rSs[e1];
        const float fT = (rT < 0) ? 0.0f : 1.0f;
        const float fS = (rS < 0) ? 0.0f : 1.0f;
        const float* qrow = qr + (size_t)nodeI * CP;
        const float* rrow = qr + (size_t)(1024 + nodeJ0 + e1) * CP;
        const float* wTr  = W1 + (size_t)(rT < 0 ? 0 : rT) * CP;
        const float* wSr  = W1 + (size_t)(rS < 0 ? 0 : rS) * CP;
        #pragma unroll
        for (int ch = 0; ch < 4; ++ch) {
            const int c0 = cb * 32 + ch * 8;
            const float4 qa = *(const float4*)&qrow[c0];
            const float4 qb = *(const float4*)&qrow[c0 + 4];
            const float4 ra = *(const float4*)&rrow[c0];
            const float4 rb = *(const float4*)&rrow[c0 + 4];
            const float4 ta = *(const float4*)&wTr[c0];
            const float4 tb = *(const float4*)&wTr[c0 + 4];
            const float4 sa = *(const float4*)&wSr[c0];
            const float4 sb = *(const float4*)&wSr[c0 + 4];
            float h[8];
            h[0] = fmaxf(qa.x + ra.x + fT * ta.x + fS * sa.x, 0.0f);
            h[1] = fmaxf(qa.y + ra.y + fT * ta.y + fS * sa.y, 0.0f);
            h[2] = fmaxf(qa.z + ra.z + fT * ta.z + fS * sa.z, 0.0f);
            h[3] = fmaxf(qa.w + ra.w + fT * ta.w + fS * sa.w, 0.0f);
            h[4] = fmaxf(qb.x + rb.x + fT * tb.x + fS * sb.x, 0.0f);
            h[5] = fmaxf(qb.y + rb.y + fT * tb.y + fS * sb.y, 0.0f);
            h[6] = fmaxf(qb.z + rb.z + fT * tb.z + fS * sb.z, 0.0f);
            h[7] = fmaxf(qb.w + rb.w + fT * tb.w + fS * sb.w, 0.0f);
            bf16x8 H, L;
            #pragma unroll
            for (int u = 0; u < 8; ++u) {
                const unsigned short hi = f2bf_rne(h[u]);
                H[u] = (short)hi;
                L[u] = (short)f2bf_rne(h[u] - bf2f(hi));
            }
            const unsigned int ad = (unsigned int)e1 * 256 +
                (((unsigned int)c0 * 2) ^ (((unsigned int)e1 & 7) << 4));
            *(bf16x8*)(hb8 + ad) = H;
            *(bf16x8*)(hb8 + 16384 + ad) = L;
        }
    }
    __syncthreads();

    const int w  = t >> 6;        // wave id: owns n in [32w, 32w+32)
    const int l  = t & 63;
    const int lr = l & 15;
    const int lg = l >> 4;
    const f32x4 zero4 = {0.0f, 0.0f, 0.0f, 0.0f};

    // ---- P2: layer 2 MFMA: C2[n][e] = sum_c W2[c][n] * h1[c][e] ----
    f32x4 acc[2][4];
    #pragma unroll
    for (int mt = 0; mt < 2; ++mt)
        #pragma unroll
        for (int nt = 0; nt < 4; ++nt) acc[mt][nt] = zero4;

    #pragma unroll
    for (int ki = 0; ki < 4; ++ki) {
        bf16x8 ah[2], al[2];
        #pragma unroll
        for (int mt = 0; mt < 2; ++mt) {
            const int mtg = 2 * w + mt;
            const size_t off = (((size_t)ki * 8 + mtg) * 64 + l) * 8;
            ah[mt] = *(const bf16x8*)(Wp + off);
            al[mt] = *(const bf16x8*)(Wp + 16384 + off);
        }
        bf16x8 bh[4], bl[4];
        #pragma unroll
        for (int nt = 0; nt < 4; ++nt) {
            const int e = 16 * nt + lr;
            const unsigned int ad = (unsigned int)e * 256 +
                (((unsigned int)(64 * ki + 16 * lg)) ^ (((unsigned int)e & 7) << 4));
            bh[nt] = *(const bf16x8*)(hb8 + ad);
            bl[nt] = *(const bf16x8*)(hb8 + 16384 + ad);
        }
        #pragma unroll
        for (int mt = 0; mt < 2; ++mt)
            #pragma unroll
            for (int nt = 0; nt < 4; ++nt) {
                acc[mt][nt] = __builtin_amdgcn_mfma_f32_16x16x32_bf16(ah[mt], bh[nt], acc[mt][nt], 0, 0, 0);
                acc[mt][nt] = __builtin_amdgcn_mfma_f32_16x16x32_bf16(al[mt], bh[nt], acc[mt][nt], 0, 0, 0);
                acc[mt][nt] = __builtin_amdgcn_mfma_f32_16x16x32_bf16(ah[mt], bl[nt], acc[mt][nt], 0, 0, 0);
            }
    }
    __syncthreads();   // all waves done reading h1

    // ---- P3: h2 = relu(C2 + b2), split, store transposed [e][n] ----
    #pragma unroll
    for (int mt = 0; mt < 2; ++mt) {
        const int mtg = 2 * w + mt;
        const float4 bv = *(const float4*)&b2[16 * mtg + 4 * lg];
        #pragma unroll
        for (int nt = 0; nt < 4; ++nt) {
            const int e = 16 * nt + lr;
            float v[4];
            v[0] = fmaxf(acc[mt][nt][0] + bv.x, 0.0f);
            v[1] = fmaxf(acc[mt][nt][1] + bv.y, 0.0f);
            v[2] = fmaxf(acc[mt][nt][2] + bv.z, 0.0f);
            v[3] = fmaxf(acc[mt][nt][3] + bv.w, 0.0f);
            bf16x4 H, L;
            #pragma unroll
            for (int u = 0; u < 4; ++u) {
                const unsigned short hi = f2bf_rne(v[u]);
                H[u] = (short)hi;
                L[u] = (short)f2bf_rne(v[u] - bf2f(hi));
            }
            const unsigned int ad = (unsigned int)e * 256 +
                (((unsigned int)(32 * mtg + 8 * lg)) ^ (((unsigned int)e & 7) << 4));
            *(bf16x4*)(hb8 + ad) = H;
            *(bf16x4*)(hb8 + 16384 + ad) = L;
        }
    }
    __syncthreads();

    // ---- P4: layer 3 MFMA: C3[n][e] = sum_k W3[k][n] * h2[k][e] ----
    f32x4 acc3[2][4];
    #pragma unroll
    for (int mt = 0; mt < 2; ++mt)
        #pragma unroll
        for (int nt = 0; nt < 4; ++nt) acc3[mt][nt] = zero4;

    #pragma unroll
    for (int ki = 0; ki < 4; ++ki) {
        bf16x8 ah[2], al[2];
        #pragma unroll
        for (int mt = 0; mt < 2; ++mt) {
            const int mtg = 2 * w + mt;
            const size_t off = (((size_t)ki * 8 + mtg) * 64 + l) * 8;
            ah[mt] = *(const bf16x8*)(Wp + 32768 + off);
            al[mt] = *(const bf16x8*)(Wp + 49152 + off);
        }
        bf16x8 bh[4], bl[4];
        #pragma unroll
        for (int nt = 0; nt < 4; ++nt) {
            const int e = 16 * nt + lr;
            const unsigned int ad = (unsigned int)e * 256 +
                (((unsigned int)(64 * ki + 16 * lg)) ^ (((unsigned int)e & 7) << 4));
            bh[nt] = *(const bf16x8*)(hb8 + ad);
            bl[nt] = *(const bf16x8*)(hb8 + 16384 + ad);
        }
        #pragma unroll
        for (int mt = 0; mt < 2; ++mt)
            #pragma unroll
            for (int nt = 0; nt < 4; ++nt) {
                acc3[mt][nt] = __builtin_amdgcn_mfma_f32_16x16x32_bf16(ah[mt], bh[nt], acc3[mt][nt], 0, 0, 0);
                acc3[mt][nt] = __builtin_amdgcn_mfma_f32_16x16x32_bf16(al[mt], bh[nt], acc3[mt][nt], 0, 0, 0);
                acc3[mt][nt] = __builtin_amdgcn_mfma_f32_16x16x32_bf16(ah[mt], bl[nt], acc3[mt][nt], 0, 0, 0);
            }
    }
    __syncthreads();   // all waves done reading h2

    // ---- P5: h3 = C3 + b3 (fp32) -> LDS [64 e][128 n] swizzled ----
    #pragma unroll
    for (int mt = 0; mt < 2; ++mt) {
        const int mtg = 2 * w + mt;
        const float4 bv = *(const float4*)&b3[16 * mtg + 4 * lg];
        #pragma unroll
        for (int nt = 0; nt < 4; ++nt) {
            const int e = 16 * nt + lr;
            float4 vv;
            vv.x = acc3[mt][nt][0] + bv.x;
            vv.y = acc3[mt][nt][1] + bv.y;
            vv.z = acc3[mt][nt][2] + bv.z;
            vv.w = acc3[mt][nt][3] + bv.w;
            const unsigned int ad = (unsigned int)e * 512 +
                (((unsigned int)(64 * mtg + 16 * lg)) ^ (((unsigned int)e & 7) << 4));
            *(float4*)(hb8 + ad) = vv;
        }
    }
    __syncthreads();

    // ---- P6: LayerNorm (exact fp32), mask, coalesced store ----
    {
        const int e  = t >> 2;
        const int c0 = (t & 3) * 32;
        float vals[32];
        float s = 0.0f;
        #pragma unroll
        for (int cc = 0; cc < 32; cc += 4) {
            const unsigned int ad = (unsigned int)e * 512 +
                (((unsigned int)((c0 + cc) * 4)) ^ (((unsigned int)e & 7) << 4));
            const float4 v = *(const float4*)(hb8 + ad);
            vals[cc] = v.x; vals[cc + 1] = v.y; vals[cc + 2] = v.z; vals[cc + 3] = v.w;
            s += v.x + v.y + v.z + v.w;
        }
        s += __shfl_xor(s, 1);
        s += __shfl_xor(s, 2);
        const float mu = s * (1.0f / 128.0f);
        float s2 = 0.0f;
        #pragma unroll
        for (int cc = 0; cc < 32; ++cc) {
            const float d = vals[cc] - mu;
            s2 = fmaf(d, d, s2);
        }
        s2 += __shfl_xor(s2, 1);
        s2 += __shfl_xor(s2, 2);
        const float inv = rsqrtf(s2 * (1.0f / 128.0f) + 1e-5f);
        const size_t erow = ((size_t)(b * NN + i)) * NN + (j0 + e);
        const float em = edge_mask[erow];
        float* op = out + erow * CP + c0;
        #pragma unroll
        for (int cc = 0; cc < 32; cc += 4) {
            const float4 g  = *(const float4*)&ln_g[c0 + cc];
            const float4 be = *(const float4*)&ln_b[c0 + cc];
            float4 o4;
            o4.x = ((vals[cc + 0] - mu) * inv * g.x + be.x) * em;
            o4.y = ((vals[cc + 1] - mu) * inv * g.y + be.y) * em;
            o4.z = ((vals[cc + 2] - mu) * inv * g.z + be.z) * em;
            o4.w = ((vals[cc + 3] - mu) * inv * g.w + be.w) * em;
            *(float4*)&op[cc] = o4;
        }
    }
}

extern "C" void kernel_launch(void* const* d_in, const int* in_sizes, int n_in,
                              void* d_out, int out_size, void* d_ws, size_t ws_size,
                              hipStream_t stream) {
    const float* init_node = (const float*)d_in[0];
    const float* trans_t   = (const float*)d_in[1];
    const float* trans_sc  = (const float*)d_in[2];
    const float* edge_mask = (const float*)d_in[3];
    const float* diffuse   = (const float*)d_in[4];
    const float* Wsp       = (const float*)d_in[5];
    const float* bsp       = (const float*)d_in[6];
    const float* W1        = (const float*)d_in[7];
    const float* b1        = (const float*)d_in[8];
    const float* W2        = (const float*)d_in[9];
    const float* b2        = (const float*)d_in[10];
    const float* W3        = (const float*)d_in[11];
    const float* b3        = (const float*)d_in[12];
    const float* ln_g      = (const float*)d_in[13];
    const float* ln_b      = (const float*)d_in[14];
    float* out = (float*)d_out;
    float* qr  = (float*)d_ws;                                   // 1 MiB
    unsigned short* Wp = (unsigned short*)((char*)d_ws + (1 << 20)); // 128 KiB

    ef_node_kernel<<<NB * NN, 256, 0, stream>>>(init_node, diffuse, Wsp, bsp, W1, b1, qr);
    ef_pack_kernel<<<64, 256, 0, stream>>>(W2, W3, Wp);
    ef_edge_kernel<<<NB * NN * (NN / EPB), 256, 0, stream>>>(
        trans_t, trans_sc, edge_mask, W1, b2, b3, ln_g, ln_b, qr, Wp, out);
}

// Round 3
// 222.598 us; speedup vs baseline: 2.9986x; 1.1540x over previous
//
#include <hip/hip_runtime.h>
#include <math.h>

#define NB 2
#define NN 512
#define CS 256
#define CP 128
#define FD 64
#define NBINS 22
#define EPB 64

typedef __attribute__((ext_vector_type(8))) short bf16x8;
typedef __attribute__((ext_vector_type(4))) short bf16x4;
typedef __attribute__((ext_vector_type(4))) float f32x4;

__device__ __forceinline__ unsigned short f2bf_rne(float x) {
    unsigned int u = __float_as_uint(x);
    unsigned int r = (u + 0x7fffu + ((u >> 16) & 1u)) >> 16;
    return (unsigned short)r;
}
__device__ __forceinline__ float bf2f(unsigned short b) {
    return __uint_as_float(((unsigned int)b) << 16);
}

// Guarded-floor bin: returns k in [0,21] s.t. lo_k < d < hi_k (exact fp32
// boundary semantics identical to the reference 22-way scan), else -1.
__device__ __forceinline__ int bin_of(float d, float step) {
    const float fk = __fdiv_rn(__fsub_rn(d, 0.001f), step);
    int k0 = (int)fk;
    k0 = k0 < 1 ? 1 : (k0 > 20 ? 20 : k0);
    int row = -1;
    #pragma unroll
    for (int dk = -1; dk <= 1; ++dk) {
        const int k = k0 + dk;
        const float lo = __fadd_rn(0.001f, __fmul_rn((float)k, step));
        const float hi = (k == NBINS - 1)
                       ? 1e8f
                       : __fadd_rn(0.001f, __fmul_rn((float)(k + 1), step));
        row = (d > lo && d < hi) ? k : row;
    }
    return row;
}

// ---------------------------------------------------------------------------
// Prep kernel: blocks [0,1024) = per-node q/r precompute; [1024,1088) = W pack.
// ---------------------------------------------------------------------------
__global__ __launch_bounds__(256) void ef_prep_kernel(
    const float* __restrict__ x,
    const float* __restrict__ diffuse,
    const float* __restrict__ Wsp,
    const float* __restrict__ bsp,
    const float* __restrict__ W1,
    const float* __restrict__ b1,
    const float* __restrict__ W2,
    const float* __restrict__ W3,
    float* __restrict__ qr,
    unsigned short* __restrict__ Wp)
{
    __shared__ float xs[CS];
    __shared__ float ps[FD];
    const int t = threadIdx.x;
    if (blockIdx.x < 1024) {
        const int n = blockIdx.x;
        xs[t] = x[(size_t)n * CS + t];
        __syncthreads();
        if (t < FD) {
            float acc = bsp[t];
            #pragma unroll 8
            for (int k = 0; k < CS; ++k)
                acc = fmaf(xs[k], Wsp[k * FD + t], acc);
            ps[t] = acc;
        }
        __syncthreads();
        const float dm = diffuse[n];
        const int c = t & (CP - 1);
        if (t < CP) {
            float acc = b1[c] + dm * W1[172 * CP + c];
            #pragma unroll 8
            for (int k = 0; k < FD; ++k)
                acc = fmaf(ps[k], W1[k * CP + c], acc);
            qr[(size_t)n * CP + c] = acc;
        } else {
            float acc = dm * W1[173 * CP + c];
            #pragma unroll 8
            for (int k = 0; k < FD; ++k)
                acc = fmaf(ps[k], W1[(FD + k) * CP + c], acc);
            qr[(size_t)(1024 + n) * CP + c] = acc;
        }
    } else {
        // pack W2,W3 into per-lane A-fragment order, bf16 hi/lo
        const int s = (blockIdx.x - 1024) * 256 + t;   // 0..16383
        const int j    = s & 7;
        const int lane = (s >> 3) & 63;
        const int mt   = (s >> 9) & 7;
        const int ki   = s >> 12;
        const int k = 32 * ki + 8 * (lane >> 4) + j;
        const int n = 16 * mt + (lane & 15);
        const float w2 = W2[k * CP + n];
        const float w3 = W3[k * CP + n];
        const unsigned short h2 = f2bf_rne(w2);
        const unsigned short l2 = f2bf_rne(w2 - bf2f(h2));
        const unsigned short h3 = f2bf_rne(w3);
        const unsigned short l3 = f2bf_rne(w3 - bf2f(h3));
        Wp[s]         = h2;
        Wp[16384 + s] = l2;
        Wp[32768 + s] = h3;
        Wp[49152 + s] = l3;
    }
}

// ---------------------------------------------------------------------------
// Edge kernel: 64 edges x 128 channels per block, 256 threads = 4 waves.
// Phases: bins+h1 | MFMA L2 | h2 | MFMA L3 | LN-partials | LN-reduce | store
// ---------------------------------------------------------------------------
__global__ __launch_bounds__(256, 4) void ef_edge_kernel(
    const float* __restrict__ trans_t,
    const float* __restrict__ trans_sc,
    const float* __restrict__ edge_mask,
    const float* __restrict__ W1,
    const float* __restrict__ b2,
    const float* __restrict__ b3,
    const float* __restrict__ ln_g,
    const float* __restrict__ ln_b,
    const float* __restrict__ qr,
    const unsigned short* __restrict__ Wp,
    float* __restrict__ out)
{
    __shared__ unsigned short hb[16384];   // exactly 32768 B
    char* hb8 = (char*)hb;

    const int t   = threadIdx.x;
    const int blk = blockIdx.x;
    const int jt  = blk & 7;
    const int i   = (blk >> 3) & (NN - 1);
    const int b   = blk >> 12;
    const int j0  = jt * EPB;
    const int nodeI  = b * NN + i;
    const int nodeJ0 = b * NN + j0;

    const int w  = t >> 6;
    const int l  = t & 63;
    const int lr = l & 15;
    const int lg = l >> 4;

    // ---- prefetch W2 hi-fragments (issue before anything else) ----
    bf16x8 w2h[4][2];
    #pragma unroll
    for (int ki = 0; ki < 4; ++ki)
        #pragma unroll
        for (int mt = 0; mt < 2; ++mt)
            w2h[ki][mt] = *(const bf16x8*)(Wp + (((size_t)ki * 8 + (2 * w + mt)) * 64 + l) * 8);

    // ---- per-thread distogram bins (4x redundant, no LDS, no barrier) ----
    const int e1 = t >> 2;
    const int c0 = (t & 3) * 32;
    const int nj = nodeJ0 + e1;
    const float step = __fdiv_rn(__fsub_rn(20.0f, 0.001f), 21.0f);
    const float ix0 = trans_t[nodeI * 3 + 0], ix1 = trans_t[nodeI * 3 + 1], ix2 = trans_t[nodeI * 3 + 2];
    const float jx0 = trans_t[nj * 3 + 0],    jx1 = trans_t[nj * 3 + 1],    jx2 = trans_t[nj * 3 + 2];
    const float iy0 = trans_sc[nodeI * 3 + 0], iy1 = trans_sc[nodeI * 3 + 1], iy2 = trans_sc[nodeI * 3 + 2];
    const float jy0 = trans_sc[nj * 3 + 0],    jy1 = trans_sc[nj * 3 + 1],    jy2 = trans_sc[nj * 3 + 2];
    float dx = __fsub_rn(ix0, jx0), dy = __fsub_rn(ix1, jx1), dz = __fsub_rn(ix2, jx2);
    const float dT = sqrtf(__fadd_rn(__fadd_rn(__fmul_rn(dx, dx), __fmul_rn(dy, dy)), __fmul_rn(dz, dz)));
    dx = __fsub_rn(iy0, jy0); dy = __fsub_rn(iy1, jy1); dz = __fsub_rn(iy2, jy2);
    const float dS = sqrtf(__fadd_rn(__fadd_rn(__fmul_rn(dx, dx), __fmul_rn(dy, dy)), __fmul_rn(dz, dz)));
    const int kT = bin_of(dT, step);
    const int kS = bin_of(dS, step);

    // ---- P1: h1 = relu(q_i + r_j + W1[binT] + W1[binS]), bf16 hi/lo -> LDS ----
    {
        const float fT = (kT < 0) ? 0.0f : 1.0f;
        const float fS = (kS < 0) ? 0.0f : 1.0f;
        const float* qrow = qr + (size_t)nodeI * CP + c0;
        const float* rrow = qr + (size_t)(1024 + nj) * CP + c0;
        const float* wTr  = W1 + (size_t)(kT < 0 ? 0 : 128 + kT) * CP + c0;
        const float* wSr  = W1 + (size_t)(kS < 0 ? 0 : 150 + kS) * CP + c0;
        #pragma unroll
        for (int ch = 0; ch < 4; ++ch) {
            const int cc = ch * 8;
            const float4 qa = *(const float4*)(qrow + cc);
            const float4 qb = *(const float4*)(qrow + cc + 4);
            const float4 ra = *(const float4*)(rrow + cc);
            const float4 rb = *(const float4*)(rrow + cc + 4);
            const float4 ta = *(const float4*)(wTr + cc);
            const float4 tb = *(const float4*)(wTr + cc + 4);
            const float4 sa = *(const float4*)(wSr + cc);
            const float4 sb = *(const float4*)(wSr + cc + 4);
            float h[8];
            h[0] = fmaxf(qa.x + ra.x + fT * ta.x + fS * sa.x, 0.0f);
            h[1] = fmaxf(qa.y + ra.y + fT * ta.y + fS * sa.y, 0.0f);
            h[2] = fmaxf(qa.z + ra.z + fT * ta.z + fS * sa.z, 0.0f);
            h[3] = fmaxf(qa.w + ra.w + fT * ta.w + fS * sa.w, 0.0f);
            h[4] = fmaxf(qb.x + rb.x + fT * tb.x + fS * sb.x, 0.0f);
            h[5] = fmaxf(qb.y + rb.y + fT * tb.y + fS * sb.y, 0.0f);
            h[6] = fmaxf(qb.z + rb.z + fT * tb.z + fS * sb.z, 0.0f);
            h[7] = fmaxf(qb.w + rb.w + fT * tb.w + fS * sb.w, 0.0f);
            bf16x8 H, L;
            #pragma unroll
            for (int u = 0; u < 8; ++u) {
                const unsigned short hi = f2bf_rne(h[u]);
                H[u] = (short)hi;
                L[u] = (short)f2bf_rne(h[u] - bf2f(hi));
            }
            const unsigned int ad = (unsigned int)e1 * 256 +
                (((unsigned int)(2 * (c0 + cc))) ^ (((unsigned int)e1 & 7) << 4));
            *(bf16x8*)(hb8 + ad) = H;
            *(bf16x8*)(hb8 + 16384 + ad) = L;
        }
    }

    // ---- prefetch W2 lo-fragments (latency hides under barrier + first MFMAs)
    bf16x8 w2l[4][2];
    #pragma unroll
    for (int ki = 0; ki < 4; ++ki)
        #pragma unroll
        for (int mt = 0; mt < 2; ++mt)
            w2l[ki][mt] = *(const bf16x8*)(Wp + 16384 + (((size_t)ki * 8 + (2 * w + mt)) * 64 + l) * 8);
    __syncthreads();

    // ---- P2: layer-2 MFMA, acc initialized with b2 ----
    f32x4 acc[2][4];
    #pragma unroll
    for (int mt = 0; mt < 2; ++mt) {
        const float4 bv = *(const float4*)&b2[16 * (2 * w + mt) + 4 * lg];
        #pragma unroll
        for (int nt = 0; nt < 4; ++nt) {
            acc[mt][nt][0] = bv.x; acc[mt][nt][1] = bv.y;
            acc[mt][nt][2] = bv.z; acc[mt][nt][3] = bv.w;
        }
    }
    #pragma unroll
    for (int ki = 0; ki < 4; ++ki) {
        bf16x8 bh[4], bl[4];
        #pragma unroll
        for (int nt = 0; nt < 4; ++nt) {
            const int e = 16 * nt + lr;
            const unsigned int ad = (unsigned int)e * 256 +
                (((unsigned int)(64 * ki + 16 * lg)) ^ (((unsigned int)e & 7) << 4));
            bh[nt] = *(const bf16x8*)(hb8 + ad);
            bl[nt] = *(const bf16x8*)(hb8 + 16384 + ad);
        }
        __builtin_amdgcn_s_setprio(1);
        #pragma unroll
        for (int mt = 0; mt < 2; ++mt)
            #pragma unroll
            for (int nt = 0; nt < 4; ++nt) {
                acc[mt][nt] = __builtin_amdgcn_mfma_f32_16x16x32_bf16(w2h[ki][mt], bh[nt], acc[mt][nt], 0, 0, 0);
                acc[mt][nt] = __builtin_amdgcn_mfma_f32_16x16x32_bf16(w2l[ki][mt], bh[nt], acc[mt][nt], 0, 0, 0);
                acc[mt][nt] = __builtin_amdgcn_mfma_f32_16x16x32_bf16(w2h[ki][mt], bl[nt], acc[mt][nt], 0, 0, 0);
            }
        __builtin_amdgcn_s_setprio(0);
    }

    // ---- prefetch W3 hi-fragments (hide under barrier + P3) ----
    bf16x8 w3h[4][2];
    #pragma unroll
    for (int ki = 0; ki < 4; ++ki)
        #pragma unroll
        for (int mt = 0; mt < 2; ++mt)
            w3h[ki][mt] = *(const bf16x8*)(Wp + 32768 + (((size_t)ki * 8 + (2 * w + mt)) * 64 + l) * 8);
    __syncthreads();   // all waves done reading h1

    // ---- P3: h2 = relu(acc), split, store transposed [e][n] ----
    #pragma unroll
    for (int mt = 0; mt < 2; ++mt) {
        const int mtg = 2 * w + mt;
        #pragma unroll
        for (int nt = 0; nt < 4; ++nt) {
            const int e = 16 * nt + lr;
            float v[4];
            v[0] = fmaxf(acc[mt][nt][0], 0.0f);
            v[1] = fmaxf(acc[mt][nt][1], 0.0f);
            v[2] = fmaxf(acc[mt][nt][2], 0.0f);
            v[3] = fmaxf(acc[mt][nt][3], 0.0f);
            bf16x4 H, L;
            #pragma unroll
            for (int u = 0; u < 4; ++u) {
                const unsigned short hi = f2bf_rne(v[u]);
                H[u] = (short)hi;
                L[u] = (short)f2bf_rne(v[u] - bf2f(hi));
            }
            const unsigned int ad = (unsigned int)e * 256 +
                (((unsigned int)(32 * mtg + 8 * lg)) ^ (((unsigned int)e & 7) << 4));
            *(bf16x4*)(hb8 + ad) = H;
            *(bf16x4*)(hb8 + 16384 + ad) = L;
        }
    }

    // ---- prefetch W3 lo-fragments ----
    bf16x8 w3l[4][2];
    #pragma unroll
    for (int ki = 0; ki < 4; ++ki)
        #pragma unroll
        for (int mt = 0; mt < 2; ++mt)
            w3l[ki][mt] = *(const bf16x8*)(Wp + 49152 + (((size_t)ki * 8 + (2 * w + mt)) * 64 + l) * 8);
    __syncthreads();

    // ---- P4: layer-3 MFMA, acc3 initialized with b3 ----
    f32x4 acc3[2][4];
    #pragma unroll
    for (int mt = 0; mt < 2; ++mt) {
        const float4 bv = *(const float4*)&b3[16 * (2 * w + mt) + 4 * lg];
        #pragma unroll
        for (int nt = 0; nt < 4; ++nt) {
            acc3[mt][nt][0] = bv.x; acc3[mt][nt][1] = bv.y;
            acc3[mt][nt][2] = bv.z; acc3[mt][nt][3] = bv.w;
        }
    }
    #pragma unroll
    for (int ki = 0; ki < 4; ++ki) {
        bf16x8 bh[4], bl[4];
        #pragma unroll
        for (int nt = 0; nt < 4; ++nt) {
            const int e = 16 * nt + lr;
            const unsigned int ad = (unsigned int)e * 256 +
                (((unsigned int)(64 * ki + 16 * lg)) ^ (((unsigned int)e & 7) << 4));
            bh[nt] = *(const bf16x8*)(hb8 + ad);
            bl[nt] = *(const bf16x8*)(hb8 + 16384 + ad);
        }
        __builtin_amdgcn_s_setprio(1);
        #pragma unroll
        for (int mt = 0; mt < 2; ++mt)
            #pragma unroll
            for (int nt = 0; nt < 4; ++nt) {
                acc3[mt][nt] = __builtin_amdgcn_mfma_f32_16x16x32_bf16(w3h[ki][mt], bh[nt], acc3[mt][nt], 0, 0, 0);
                acc3[mt][nt] = __builtin_amdgcn_mfma_f32_16x16x32_bf16(w3l[ki][mt], bh[nt], acc3[mt][nt], 0, 0, 0);
                acc3[mt][nt] = __builtin_amdgcn_mfma_f32_16x16x32_bf16(w3h[ki][mt], bl[nt], acc3[mt][nt], 0, 0, 0);
            }
        __builtin_amdgcn_s_setprio(0);
    }
    __syncthreads();   // all waves done reading h2; hb reusable for LN partials

    // ---- P5: LN partial sums (per-lane over its 8 n-values per edge) ----
    float* psum_s  = (float*)hb8;            // [64][17]
    float* pqsum_s = (float*)(hb8 + 4352);   // [64][17]
    float* mus     = (float*)(hb8 + 8704);   // [64]
    float* invs    = (float*)(hb8 + 8960);   // [64]
    #pragma unroll
    for (int nt = 0; nt < 4; ++nt) {
        const int e = 16 * nt + lr;
        float s = 0.0f, s2 = 0.0f;
        #pragma unroll
        for (int mt = 0; mt < 2; ++mt)
            #pragma unroll
            for (int r = 0; r < 4; ++r) {
                const float v = acc3[mt][nt][r];
                s += v;
                s2 = fmaf(v, v, s2);
            }
        psum_s[e * 17 + 4 * w + lg]  = s;
        pqsum_s[e * 17 + 4 * w + lg] = s2;
    }
    __syncthreads();

    // ---- P6: LN reduce (redundant per thread, e = t & 63) ----
    {
        const int e = t & 63;
        float s = 0.0f, s2 = 0.0f;
        #pragma unroll
        for (int k = 0; k < 16; ++k) {
            s  += psum_s[e * 17 + k];
            s2 += pqsum_s[e * 17 + k];
        }
        const float mu  = s * (1.0f / 128.0f);
        const float var = s2 * (1.0f / 128.0f) - mu * mu;
        mus[e]  = mu;
        invs[e] = rsqrtf(var + 1e-5f);
    }
    __syncthreads();

    // ---- P7: normalize fragments in-register, mask, store direct to global ----
    {
        float4 g4[2], bb4[2];
        #pragma unroll
        for (int mt = 0; mt < 2; ++mt) {
            const int n0 = 16 * (2 * w + mt) + 4 * lg;
            g4[mt]  = *(const float4*)&ln_g[n0];
            bb4[mt] = *(const float4*)&ln_b[n0];
        }
        #pragma unroll
        for (int nt = 0; nt < 4; ++nt) {
            const int e = 16 * nt + lr;
            const size_t erow = ((size_t)(b * NN + i)) * NN + (j0 + e);
            const float em  = edge_mask[erow];
            const float mu  = mus[e];
            const float inv = invs[e];
            float* op = out + erow * CP;
            #pragma unroll
            for (int mt = 0; mt < 2; ++mt) {
                const int n0 = 16 * (2 * w + mt) + 4 * lg;
                float4 o;
                o.x = ((acc3[mt][nt][0] - mu) * inv * g4[mt].x + bb4[mt].x) * em;
                o.y = ((acc3[mt][nt][1] - mu) * inv * g4[mt].y + bb4[mt].y) * em;
                o.z = ((acc3[mt][nt][2] - mu) * inv * g4[mt].z + bb4[mt].z) * em;
                o.w = ((acc3[mt][nt][3] - mu) * inv * g4[mt].w + bb4[mt].w) * em;
                *(float4*)(op + n0) = o;
            }
        }
    }
}

extern "C" void kernel_launch(void* const* d_in, const int* in_sizes, int n_in,
                              void* d_out, int out_size, void* d_ws, size_t ws_size,
                              hipStream_t stream) {
    const float* init_node = (const float*)d_in[0];
    const float* trans_t   = (const float*)d_in[1];
    const float* trans_sc  = (const float*)d_in[2];
    const float* edge_mask = (const float*)d_in[3];
    const float* diffuse   = (const float*)d_in[4];
    const float* Wsp       = (const float*)d_in[5];
    const float* bsp       = (const float*)d_in[6];
    const float* W1        = (const float*)d_in[7];
    const float* b1        = (const float*)d_in[8];
    const float* W2        = (const float*)d_in[9];
    const float* b2        = (const float*)d_in[10];
    const float* W3        = (const float*)d_in[11];
    const float* b3        = (const float*)d_in[12];
    const float* ln_g      = (const float*)d_in[13];
    const float* ln_b      = (const float*)d_in[14];
    float* out = (float*)d_out;
    float* qr  = (float*)d_ws;                                       // 1 MiB
    unsigned short* Wp = (unsigned short*)((char*)d_ws + (1 << 20)); // 128 KiB

    ef_prep_kernel<<<1024 + 64, 256, 0, stream>>>(
        init_node, diffuse, Wsp, bsp, W1, b1, W2, W3, qr, Wp);
    ef_edge_kernel<<<NB * NN * (NN / EPB), 256, 0, stream>>>(
        trans_t, trans_sc, edge_mask, W1, b2, b3, ln_g, ln_b, qr, Wp, out);
}